// Round 1
// baseline (678.847 us; speedup 1.0000x reference)
//
#include <hip/hip_runtime.h>
#include <hip/hip_fp16.h>

#define N_USERS  200000
#define N_ITEMS  100000
#define N_TOPICS 100
#define N_NODES  (N_USERS + N_ITEMS + N_TOPICS)
#define DIM      64
#define BSHIFT   9                                // 512 rows per bucket
#define BROWS    (1 << BSHIFT)
#define NBUCKETS ((N_NODES + BROWS - 1) >> BSHIFT)   // 587
#define COLMASK  0x7FFFF                          // 19 bits (N_NODES < 2^19)
#define NB       512                              // binning blocks
#define NBSHIFT  9
#define M_TOT    (NBUCKETS * NB)                  // 300,544 partials
#define SB       256                              // scan blocks
#define CH       ((M_TOT + SB - 1) / SB)

// ---------- CSR build (zero global atomics) ----------

// 1024-thread blocks: 2 blocks/CU -> 32 waves/CU (was 8 waves/CU at 256).
__global__ void bucket_hist_kernel(const int* __restrict__ rows,
                                   int* __restrict__ partial, int n_edges) {
    __shared__ int h[NBUCKETS];
    for (int i = threadIdx.x; i < NBUCKETS; i += blockDim.x) h[i] = 0;
    __syncthreads();
    int n4 = n_edges >> 2;
    int stride = gridDim.x * blockDim.x;
    int gid = blockIdx.x * blockDim.x + threadIdx.x;
    const int4* r4 = (const int4*)rows;
    for (int e = gid; e < n4; e += stride) {
        int4 v = r4[e];
        atomicAdd(&h[((unsigned)v.x) >> BSHIFT], 1);
        atomicAdd(&h[((unsigned)v.y) >> BSHIFT], 1);
        atomicAdd(&h[((unsigned)v.z) >> BSHIFT], 1);
        atomicAdd(&h[((unsigned)v.w) >> BSHIFT], 1);
    }
    int tail0 = n4 << 2;
    if (gid < n_edges - tail0)
        atomicAdd(&h[((unsigned)rows[tail0 + gid]) >> BSHIFT], 1);
    __syncthreads();
    for (int i = threadIdx.x; i < NBUCKETS; i += blockDim.x)
        partial[blockIdx.x * NBUCKETS + i] = h[i];
}

// Logical L = bucket*NB + block; physical = block*NBUCKETS + bucket.
__device__ __forceinline__ int phys_idx(int L) {
    return (L & (NB - 1)) * NBUCKETS + (L >> NBSHIFT);
}

__global__ void scanB1_kernel(const int* __restrict__ partial,
                              int* __restrict__ psum) {
    __shared__ int s[256];
    int tid = threadIdx.x;
    int c0 = blockIdx.x * CH;
    int c1 = min(M_TOT, c0 + CH);
    int sum = 0;
    for (int L = c0 + tid; L < c1; L += 256) sum += partial[phys_idx(L)];
    s[tid] = sum;
    __syncthreads();
    for (int off = 128; off > 0; off >>= 1) {
        if (tid < off) s[tid] += s[tid + off];
        __syncthreads();
    }
    if (tid == 0) psum[blockIdx.x] = s[0];
}

// scanB2 folded in: each block reduces psum[0..bid) itself (256 ints, cheap).
__global__ void scanB3_kernel(const int* __restrict__ partial,
                              const int* __restrict__ psum,
                              int* __restrict__ offs) {
    __shared__ int s[SB];
    __shared__ int tile[256];
    __shared__ int carry;
    int tid = threadIdx.x;
    s[tid] = (tid < blockIdx.x) ? psum[tid] : 0;
    __syncthreads();
    for (int off = 128; off > 0; off >>= 1) {
        if (tid < off) s[tid] += s[tid + off];
        __syncthreads();
    }
    if (tid == 0) carry = s[0];
    __syncthreads();
    int c0 = blockIdx.x * CH;
    int c1 = min(M_TOT, c0 + CH);
    for (int base = c0; base < c1; base += 256) {
        int L = base + tid;
        int v = (L < c1) ? partial[phys_idx(L)] : 0;
        tile[tid] = v;
        __syncthreads();
        for (int off = 1; off < 256; off <<= 1) {
            int t = (tid >= off) ? tile[tid - off] : 0;
            __syncthreads();
            tile[tid] += t;
            __syncthreads();
        }
        if (L < c1) offs[L] = carry + tile[tid] - v;
        __syncthreads();
        if (tid == 255) carry += tile[255];
        __syncthreads();
    }
}

// Bin edges into 512-row buckets; split key/val arrays so scatter2's hist
// pass only reads keys. Mapping MUST match bucket_hist (same grid/stride).
__global__ void scatter1_kernel(const int* __restrict__ rows,
                                const int* __restrict__ cols,
                                const float* __restrict__ vals,
                                const int* __restrict__ offs,
                                int* __restrict__ bkt_key,
                                float* __restrict__ bkt_val, int n_edges) {
    __shared__ int lpos[NBUCKETS];
    for (int i = threadIdx.x; i < NBUCKETS; i += blockDim.x)
        lpos[i] = offs[i * NB + blockIdx.x];
    __syncthreads();
    int n4 = n_edges >> 2;
    int stride = gridDim.x * blockDim.x;
    int gid = blockIdx.x * blockDim.x + threadIdx.x;
    const int4*   r4 = (const int4*)rows;
    const int4*   c4 = (const int4*)cols;
    const float4* v4 = (const float4*)vals;
    for (int e = gid; e < n4; e += stride) {
        int4 r = r4[e];
        int4 c = c4[e];
        float4 v = v4[e];
        #pragma unroll
        for (int j = 0; j < 4; ++j) {
            int rr = (j == 0) ? r.x : (j == 1) ? r.y : (j == 2) ? r.z : r.w;
            int cc = (j == 0) ? c.x : (j == 1) ? c.y : (j == 2) ? c.z : c.w;
            float vv = (j == 0) ? v.x : (j == 1) ? v.y : (j == 2) ? v.z : v.w;
            int b = ((unsigned)rr) >> BSHIFT;
            int pos = atomicAdd(&lpos[b], 1);
            bkt_key[pos] = cc | ((rr & (BROWS - 1)) << 19);
            bkt_val[pos] = vv;
        }
    }
    int tail0 = n4 << 2;
    if (gid < n_edges - tail0) {
        int e = tail0 + gid;
        int rr = rows[e];
        int b = ((unsigned)rr) >> BSHIFT;
        int pos = atomicAdd(&lpos[b], 1);
        bkt_key[pos] = cols[e] | ((rr & (BROWS - 1)) << 19);
        bkt_val[pos] = vals[e];
    }
}

// One 1024-thread block per 512-row bucket (was 256: 4x more TLP).
__global__ void scatter2_kernel(const int* __restrict__ bkt_key,
                                const float* __restrict__ bkt_val,
                                const int* __restrict__ offs,
                                int* __restrict__ row_ptr,
                                int2* __restrict__ csr_cv, int n_edges) {
    __shared__ int lcnt[BROWS];
    __shared__ int lptr[BROWS];
    __shared__ int lfill[BROWS];
    __shared__ int s[256];
    int b = blockIdx.x;
    int t = threadIdx.x;
    int e0 = offs[b * NB];
    int e1 = (b == NBUCKETS - 1) ? n_edges : offs[(b + 1) * NB];
    for (int i = t; i < BROWS; i += blockDim.x) { lcnt[i] = 0; lfill[i] = 0; }
    __syncthreads();
    for (int e = e0 + t; e < e1; e += blockDim.x)
        atomicAdd(&lcnt[((unsigned)bkt_key[e]) >> 19], 1);
    __syncthreads();
    if (t < 256) s[t] = lcnt[2 * t] + lcnt[2 * t + 1];
    __syncthreads();
    for (int off = 1; off < 256; off <<= 1) {
        int v = 0;
        if (t < 256 && t >= off) v = s[t - off];
        __syncthreads();
        if (t < 256) s[t] += v;                 // inclusive over pairs
        __syncthreads();
    }
    if (t < 256) {
        int base = e0 + (t ? s[t - 1] : 0);
        int rbase = b << BSHIFT;
        int p_even = base;
        int p_odd  = base + lcnt[2 * t];
        lptr[2 * t]     = p_even;
        lptr[2 * t + 1] = p_odd;
        if (rbase + 2 * t     < N_NODES) row_ptr[rbase + 2 * t]     = p_even;
        if (rbase + 2 * t + 1 < N_NODES) row_ptr[rbase + 2 * t + 1] = p_odd;
    }
    if (b == NBUCKETS - 1 && t == 0) row_ptr[N_NODES] = n_edges;
    __syncthreads();
    for (int e = e0 + t; e < e1; e += blockDim.x) {
        int k = bkt_key[e];
        float v = bkt_val[e];
        int delta = ((unsigned)k) >> 19;
        int pos = lptr[delta] + atomicAdd(&lfill[delta], 1);
        int2 cv;
        cv.x = k & COLMASK;
        cv.y = __float_as_int(v);
        csr_cv[pos] = cv;
    }
}

// ---------- h0 = fp16(concat(user, item, topic)) ----------
__global__ void concat_f16_kernel(const float* __restrict__ uemb,
                                  const float* __restrict__ iemb,
                                  const float* __restrict__ temb,
                                  ushort* __restrict__ h0) {
    int g = blockIdx.x * blockDim.x + threadIdx.x;     // group of 4 elems
    long base = (long)g * 4;
    if (base >= (long)N_NODES * DIM) return;
    const float* src;
    long off;
    if (base < (long)N_USERS * DIM)                 { src = uemb; off = base; }
    else if (base < (long)(N_USERS + N_ITEMS) * DIM){ src = iemb; off = base - (long)N_USERS * DIM; }
    else                                            { src = temb; off = base - (long)(N_USERS + N_ITEMS) * DIM; }
    float4 v = *(const float4*)(src + off);
    __half2 a = __floats2half2_rn(v.x, v.y);
    __half2 b = __floats2half2_rn(v.z, v.w);
    uint2 o;
    o.x = *(unsigned*)&a;
    o.y = *(unsigned*)&b;
    ((uint2*)h0)[g] = o;
}

// ---------- SpMV helpers ----------
__device__ __forceinline__ int2 ld_nt_int2(const int2* __restrict__ p) {
    unsigned long long v =
        __builtin_nontemporal_load((const unsigned long long*)p);
    int2 r;
    r.x = (int)(unsigned)v;
    r.y = (int)(v >> 32);
    return r;
}

// fmaf(half2float(h), w, acc) lowers to v_fma_mix_f32 (fp16 src, fp32 MAC).
__device__ __forceinline__ float4 fma_mix4(const ushort* __restrict__ h,
                                           int row, int l16, float w,
                                           float4 acc) {
    uint2 r = ((const uint2*)(h + (size_t)row * DIM))[l16];
    __half2 h01 = *(__half2*)&r.x;
    __half2 h23 = *(__half2*)&r.y;
    acc.x = __builtin_fmaf(__half2float(__low2half(h01)),  w, acc.x);
    acc.y = __builtin_fmaf(__half2float(__high2half(h01)), w, acc.y);
    acc.z = __builtin_fmaf(__half2float(__low2half(h23)),  w, acc.z);
    acc.w = __builtin_fmaf(__half2float(__high2half(h23)), w, acc.w);
    return acc;
}

// Full-table SpMV: 4 rows/wave (1 per 16-lane group), 8 edges in flight.
// cv stream + h_dst store are non-temporal: keep L2 for the h gathers.
__global__ void spmv_csr_kernel(const int* __restrict__ row_ptr,
                                const int2* __restrict__ csr_cv,
                                const ushort* __restrict__ h_src,
                                ushort* __restrict__ h_dst) {
    int wave = (int)(((long)blockIdx.x * blockDim.x + threadIdx.x) >> 6);
    int lane = threadIdx.x & 63;
    int g    = lane >> 4;
    int l16  = lane & 15;
    int r    = wave * 4 + g;
    int rc   = min(r, N_NODES - 1);
    int p0   = row_ptr[rc];
    int p1   = row_ptr[rc + 1];
    int len  = (r < N_NODES) ? (p1 - p0) : 0;
    int m = max(len, __shfl_xor(len, 16, 64));
    m = max(m, __shfl_xor(m, 32, 64));
    float4 acc = make_float4(0.f, 0.f, 0.f, 0.f);
    for (int off = 0; off < m; off += 8) {
        int2 cv[8];
        #pragma unroll
        for (int j = 0; j < 8; ++j) {
            bool k = (off + j) < len;
            cv[j] = ld_nt_int2(csr_cv + (k ? (p0 + off + j) : p0));
            if (!k) cv[j].y = 0;
        }
        #pragma unroll
        for (int j = 0; j < 8; ++j)
            acc = fma_mix4(h_src, cv[j].x, l16, __int_as_float(cv[j].y), acc);
    }
    if (r < N_NODES) {
        __half2 a = __floats2half2_rn(acc.x, acc.y);
        __half2 b = __floats2half2_rn(acc.z, acc.w);
        unsigned long long o =
            (unsigned long long)(*(unsigned*)&a) |
            ((unsigned long long)(*(unsigned*)&b) << 32);
        __builtin_nontemporal_store(
            o, (unsigned long long*)((uint2*)(h_dst + (size_t)r * DIM) + l16));
    }
}

// Layer-3 SpMV over BATCH ROWS ONLY (~11% of the edges).
__global__ void spmv_batch_kernel(const int* __restrict__ row_ptr,
                                  const int2* __restrict__ csr_cv,
                                  const ushort* __restrict__ h_src,
                                  const int* __restrict__ users,
                                  const int* __restrict__ items,
                                  float* __restrict__ u_acc,
                                  float* __restrict__ it_acc, int B) {
    int wave = (int)(((long)blockIdx.x * blockDim.x + threadIdx.x) >> 6);
    int lane = threadIdx.x & 63;
    int g    = lane >> 4;
    int l16  = lane & 15;
    int s    = wave * 4 + g;
    bool ok  = s < 2 * B;
    int node = 0;
    if (ok) node = (s < B) ? users[s] : (N_USERS + items[s - B]);
    int p0  = row_ptr[node];
    int p1  = row_ptr[node + 1];
    int len = ok ? (p1 - p0) : 0;
    int m = max(len, __shfl_xor(len, 16, 64));
    m = max(m, __shfl_xor(m, 32, 64));
    float4 acc = make_float4(0.f, 0.f, 0.f, 0.f);
    for (int off = 0; off < m; off += 8) {
        int2 cv[8];
        #pragma unroll
        for (int j = 0; j < 8; ++j) {
            bool k = (off + j) < len;
            cv[j] = ld_nt_int2(csr_cv + (k ? (p0 + off + j) : p0));
            if (!k) cv[j].y = 0;
        }
        #pragma unroll
        for (int j = 0; j < 8; ++j)
            acc = fma_mix4(h_src, cv[j].x, l16, __int_as_float(cv[j].y), acc);
    }
    if (ok) {
        float* dst = (s < B) ? (u_acc + (size_t)s * DIM)
                             : (it_acc + (size_t)(s - B) * DIM);
        float4* p = (float4*)dst + l16;
        float4 old = *p;
        old.x += acc.x; old.y += acc.y; old.z += acc.z; old.w += acc.w;
        *p = old;
    }
}

// ---------- batch-row accumulation (fp32 acc) + readout ----------

// Layer-0 init straight from fp32 embeddings (no fp16 round-trip).
__global__ void gather_init_kernel(const float* __restrict__ uemb,
                                   const float* __restrict__ iemb,
                                   const int* __restrict__ users,
                                   const int* __restrict__ items,
                                   float* __restrict__ u_acc,
                                   float* __restrict__ it_acc, int B) {
    int gid  = blockIdx.x * blockDim.x + threadIdx.x;
    int b    = gid >> 4;
    int lane = gid & 15;
    if (b >= B) return;
    int u  = users[b];
    int it = items[b];
    float4 uv = ((const float4*)(uemb + (size_t)u  * DIM))[lane];
    float4 iv = ((const float4*)(iemb + (size_t)it * DIM))[lane];
    ((float4*)(u_acc  + (size_t)b * DIM))[lane] = uv;
    ((float4*)(it_acc + (size_t)b * DIM))[lane] = iv;
}

__global__ void gather_add_kernel(const ushort* __restrict__ h,
                                  const int* __restrict__ users,
                                  const int* __restrict__ items,
                                  float* __restrict__ u_acc,
                                  float* __restrict__ it_acc, int B) {
    int gid  = blockIdx.x * blockDim.x + threadIdx.x;
    int b    = gid >> 4;
    int lane = gid & 15;
    if (b >= B) return;
    int u  = users[b];
    int it = N_USERS + items[b];
    uint2 ur = ((const uint2*)(h + (size_t)u  * DIM))[lane];
    uint2 ir = ((const uint2*)(h + (size_t)it * DIM))[lane];
    float2 u01 = __half22float2(*(__half2*)&ur.x);
    float2 u23 = __half22float2(*(__half2*)&ur.y);
    float2 i01 = __half22float2(*(__half2*)&ir.x);
    float2 i23 = __half22float2(*(__half2*)&ir.y);
    float4* up = (float4*)(u_acc  + (size_t)b * DIM) + lane;
    float4* ip = (float4*)(it_acc + (size_t)b * DIM) + lane;
    float4 a = *up;
    a.x += u01.x; a.y += u01.y; a.z += u23.x; a.w += u23.y;
    *up = a;
    float4 c = *ip;
    c.x += i01.x; c.y += i01.y; c.z += i23.x; c.w += i23.y;
    *ip = c;
}

__global__ void dot_kernel(const float* __restrict__ u_acc,
                           const float* __restrict__ it_acc,
                           float* __restrict__ out, int B) {
    int gid  = blockIdx.x * blockDim.x + threadIdx.x;
    int b    = gid >> 6;
    int lane = gid & 63;
    if (b >= B) return;
    float p = u_acc[(size_t)b * DIM + lane] * it_acc[(size_t)b * DIM + lane];
    #pragma unroll
    for (int off = 32; off > 0; off >>= 1)
        p += __shfl_down(p, off, 64);
    if (lane == 0) out[b] = p * (1.0f / 16.0f);
}

extern "C" void kernel_launch(void* const* d_in, const int* in_sizes, int n_in,
                              void* d_out, int out_size, void* d_ws, size_t ws_size,
                              hipStream_t stream) {
    const int*   users = (const int*)d_in[0];
    const int*   items = (const int*)d_in[1];
    const int*   erows = (const int*)d_in[2];
    const int*   ecols = (const int*)d_in[3];
    const float* evals = (const float*)d_in[4];
    const float* uemb  = (const float*)d_in[5];
    const float* iemb  = (const float*)d_in[6];
    const float* temb  = (const float*)d_in[7];
    float* out = (float*)d_out;

    const int n_edges = in_sizes[2];
    const int B       = in_sizes[0];

    const size_t h2bytes = (((size_t)N_NODES * DIM * 2 + 255) / 256) * 256;  // 38.4 MB
    const size_t abytes  = (size_t)B * DIM * sizeof(float);                  // 4.2 MB
    const size_t rpbytes = (((size_t)(N_NODES + 1) * 4 + 255) / 256) * 256;
    const size_t cvbytes = (size_t)n_edges * 8;                              // 40 MB
    const size_t kbytes  = (size_t)n_edges * 4;                              // 20 MB
    const size_t mbytes  = (((size_t)M_TOT * 4 + 255) / 256) * 256;          // 1.2 MB

    char* ws = (char*)d_ws;
    size_t off = 0;
    ushort* hA      = (ushort*)(ws + off); off += h2bytes;
    ushort* hB      = (ushort*)(ws + off); off += h2bytes;
    float*  u_acc   = (float*) (ws + off); off += abytes;
    float*  it_acc  = (float*) (ws + off); off += abytes;
    int*    row_ptr = (int*)   (ws + off); off += rpbytes;
    int2*   csr_cv  = (int2*)  (ws + off); off += cvbytes;
    int*    bkt_key = (int*)   (ws + off); off += kbytes;
    float*  bkt_val = (float*) (ws + off); off += kbytes;
    int*    partial = (int*)   (ws + off); off += mbytes;
    int*    offs    = (int*)   (ws + off); off += mbytes;
    int*    psum    = (int*)   (ws + off); off += 4096;

    dim3 blk(256);
    dim3 blk1k(1024);

    // ---- CSR build: zero global atomics ----
    bucket_hist_kernel<<<NB, blk1k, 0, stream>>>(erows, partial, n_edges);
    scanB1_kernel<<<SB, blk, 0, stream>>>(partial, psum);
    scanB3_kernel<<<SB, blk, 0, stream>>>(partial, psum, offs);
    scatter1_kernel<<<NB, blk1k, 0, stream>>>(erows, ecols, evals, offs,
                                              bkt_key, bkt_val, n_edges);
    scatter2_kernel<<<NBUCKETS, blk1k, 0, stream>>>(bkt_key, bkt_val, offs,
                                                    row_ptr, csr_cv, n_edges);

    // ---- h0 ----
    const long n4 = (long)N_NODES * DIM / 4;
    concat_f16_kernel<<<(int)((n4 + 255) / 256), blk, 0, stream>>>(uemb, iemb, temb, hA);

    const int gblocks = (B * 16 + 255) / 256;
    gather_init_kernel<<<gblocks, blk, 0, stream>>>(uemb, iemb, users, items,
                                                    u_acc, it_acc, B);

    // ---- layers 1,2: full-table SpMV; layer 3: batch rows only ----
    const int nwaves  = (N_NODES + 3) / 4;
    const int sblocks = (int)(((long)nwaves * 64 + 255) / 256);
    ushort* src = hA;
    ushort* dst = hB;
    for (int l = 0; l < 2; ++l) {
        spmv_csr_kernel<<<sblocks, blk, 0, stream>>>(row_ptr, csr_cv, src, dst);
        gather_add_kernel<<<gblocks, blk, 0, stream>>>(dst, users, items,
                                                       u_acc, it_acc, B);
        ushort* t = src; src = dst; dst = t;
    }
    // src == h2
    const int bwaves  = (2 * B + 3) / 4;
    const int bblocks = (int)(((long)bwaves * 64 + 255) / 256);
    spmv_batch_kernel<<<bblocks, blk, 0, stream>>>(row_ptr, csr_cv, src,
                                                   users, items, u_acc, it_acc, B);

    dot_kernel<<<(B * 64 + 255) / 256, blk, 0, stream>>>(u_acc, it_acc, out, B);
}

// Round 2
// 658.817 us; speedup vs baseline: 1.0304x; 1.0304x over previous
//
#include <hip/hip_runtime.h>
#include <hip/hip_fp16.h>

#define N_USERS  200000
#define N_ITEMS  100000
#define N_TOPICS 100
#define N_NODES  (N_USERS + N_ITEMS + N_TOPICS)
#define DIM      64
#define BSHIFT   9                                // 512 rows per bucket
#define BROWS    (1 << BSHIFT)
#define NBUCKETS ((N_NODES + BROWS - 1) >> BSHIFT)   // 587
#define COLMASK  0x7FFFF                          // 19 bits (N_NODES < 2^19)
#define NB       512                              // binning blocks
#define NBSHIFT  9
#define M_TOT    (NBUCKETS * NB)                  // 300,544 partials
#define SB       256                              // scan blocks
#define CH       ((M_TOT + SB - 1) / SB)

// ---------- CSR build (zero global atomics) ----------

__global__ void bucket_hist_kernel(const int* __restrict__ rows,
                                   int* __restrict__ partial, int n_edges) {
    __shared__ int h[NBUCKETS];
    for (int i = threadIdx.x; i < NBUCKETS; i += blockDim.x) h[i] = 0;
    __syncthreads();
    int stride = gridDim.x * blockDim.x;
    for (int e = blockIdx.x * blockDim.x + threadIdx.x; e < n_edges; e += stride)
        atomicAdd(&h[((unsigned)rows[e]) >> BSHIFT], 1);
    __syncthreads();
    for (int i = threadIdx.x; i < NBUCKETS; i += blockDim.x)
        partial[blockIdx.x * NBUCKETS + i] = h[i];
}

// Logical L = bucket*NB + block; physical = block*NBUCKETS + bucket.
__device__ __forceinline__ int phys_idx(int L) {
    return (L & (NB - 1)) * NBUCKETS + (L >> NBSHIFT);
}

__global__ void scanB1_kernel(const int* __restrict__ partial,
                              int* __restrict__ psum) {
    __shared__ int s[256];
    int tid = threadIdx.x;
    int c0 = blockIdx.x * CH;
    int c1 = min(M_TOT, c0 + CH);
    int sum = 0;
    for (int L = c0 + tid; L < c1; L += 256) sum += partial[phys_idx(L)];
    s[tid] = sum;
    __syncthreads();
    for (int off = 128; off > 0; off >>= 1) {
        if (tid < off) s[tid] += s[tid + off];
        __syncthreads();
    }
    if (tid == 0) psum[blockIdx.x] = s[0];
}

__global__ void scanB2_kernel(int* __restrict__ psum) {
    __shared__ int s[SB];
    int tid = threadIdx.x;
    s[tid] = psum[tid];
    __syncthreads();
    for (int off = 1; off < SB; off <<= 1) {
        int v = (tid >= off) ? s[tid - off] : 0;
        __syncthreads();
        s[tid] += v;
        __syncthreads();
    }
    psum[tid] = tid ? s[tid - 1] : 0;
}

__global__ void scanB3_kernel(const int* __restrict__ partial,
                              const int* __restrict__ psum,
                              int* __restrict__ offs) {
    __shared__ int tile[256];
    __shared__ int carry;
    int tid = threadIdx.x;
    int c0 = blockIdx.x * CH;
    int c1 = min(M_TOT, c0 + CH);
    if (tid == 0) carry = psum[blockIdx.x];
    __syncthreads();
    for (int base = c0; base < c1; base += 256) {
        int L = base + tid;
        int v = (L < c1) ? partial[phys_idx(L)] : 0;
        tile[tid] = v;
        __syncthreads();
        for (int off = 1; off < 256; off <<= 1) {
            int t = (tid >= off) ? tile[tid - off] : 0;
            __syncthreads();
            tile[tid] += t;
            __syncthreads();
        }
        if (L < c1) offs[L] = carry + tile[tid] - v;
        __syncthreads();
        if (tid == 255) carry += tile[255];
        __syncthreads();
    }
}

// Bin edges into 512-row buckets at exact positions; LDS-only atomics.
__global__ void scatter1_kernel(const int* __restrict__ rows,
                                const int* __restrict__ cols,
                                const float* __restrict__ vals,
                                const int* __restrict__ offs,
                                int2* __restrict__ bkt_buf, int n_edges) {
    __shared__ int lpos[NBUCKETS];
    for (int i = threadIdx.x; i < NBUCKETS; i += blockDim.x)
        lpos[i] = offs[i * NB + blockIdx.x];
    __syncthreads();
    int stride = gridDim.x * blockDim.x;
    for (int e = blockIdx.x * blockDim.x + threadIdx.x; e < n_edges; e += stride) {
        int r = rows[e];
        int b = ((unsigned)r) >> BSHIFT;
        int pos = atomicAdd(&lpos[b], 1);
        int2 p;
        p.x = cols[e] | ((r & (BROWS - 1)) << 19);
        p.y = __float_as_int(vals[e]);
        bkt_buf[pos] = p;
    }
}

// One block per 512-row bucket: LDS row hist, 2-elem/thread scan, emit
// row_ptr directly, place edges into the bucket's contiguous CSR span.
__global__ void scatter2_kernel(const int2* __restrict__ bkt_buf,
                                const int* __restrict__ offs,
                                int* __restrict__ row_ptr,
                                int2* __restrict__ csr_cv, int n_edges) {
    __shared__ int lcnt[BROWS];
    __shared__ int lptr[BROWS];
    __shared__ int lfill[BROWS];
    __shared__ int s[256];
    int b = blockIdx.x;
    int t = threadIdx.x;
    int e0 = offs[b * NB];
    int e1 = (b == NBUCKETS - 1) ? n_edges : offs[(b + 1) * NB];
    lcnt[t] = 0;          lcnt[t + 256] = 0;
    lfill[t] = 0;         lfill[t + 256] = 0;
    __syncthreads();
    for (int e = e0 + t; e < e1; e += blockDim.x)
        atomicAdd(&lcnt[((unsigned)bkt_buf[e].x) >> 19], 1);
    __syncthreads();
    s[t] = lcnt[2 * t] + lcnt[2 * t + 1];
    __syncthreads();
    for (int off = 1; off < 256; off <<= 1) {
        int v = (t >= off) ? s[t - off] : 0;
        __syncthreads();
        s[t] += v;                       // inclusive over pairs
        __syncthreads();
    }
    int base = e0 + (t ? s[t - 1] : 0);
    int rbase = b << BSHIFT;
    int p_even = base;
    int p_odd  = base + lcnt[2 * t];
    lptr[2 * t]     = p_even;
    lptr[2 * t + 1] = p_odd;
    if (rbase + 2 * t     < N_NODES) row_ptr[rbase + 2 * t]     = p_even;
    if (rbase + 2 * t + 1 < N_NODES) row_ptr[rbase + 2 * t + 1] = p_odd;
    if (b == NBUCKETS - 1 && t == 0) row_ptr[N_NODES] = n_edges;
    __syncthreads();
    for (int e = e0 + t; e < e1; e += blockDim.x) {
        int2 p = bkt_buf[e];
        int delta = ((unsigned)p.x) >> 19;
        int pos = lptr[delta] + atomicAdd(&lfill[delta], 1);
        int2 cv;
        cv.x = p.x & COLMASK;
        cv.y = p.y;
        csr_cv[pos] = cv;
    }
}

// ---------- h0 = fp16(concat(user, item, topic)) ----------
__global__ void concat_f16_kernel(const float* __restrict__ uemb,
                                  const float* __restrict__ iemb,
                                  const float* __restrict__ temb,
                                  ushort* __restrict__ h0) {
    int g = blockIdx.x * blockDim.x + threadIdx.x;     // group of 4 elems
    long base = (long)g * 4;
    if (base >= (long)N_NODES * DIM) return;
    const float* src;
    long off;
    if (base < (long)N_USERS * DIM)                 { src = uemb; off = base; }
    else if (base < (long)(N_USERS + N_ITEMS) * DIM){ src = iemb; off = base - (long)N_USERS * DIM; }
    else                                            { src = temb; off = base - (long)(N_USERS + N_ITEMS) * DIM; }
    float4 v = *(const float4*)(src + off);
    __half2 a = __floats2half2_rn(v.x, v.y);
    __half2 b = __floats2half2_rn(v.z, v.w);
    uint2 o;
    o.x = *(unsigned*)&a;
    o.y = *(unsigned*)&b;
    ((uint2*)h0)[g] = o;
}

// ---------- SpMV helpers ----------
// fmaf(half2float(h), w, acc) lowers to v_fma_mix_f32 (fp16 src, fp32 MAC).
__device__ __forceinline__ float4 fma_mix4(const ushort* __restrict__ h,
                                           int row, int l16, float w,
                                           float4 acc) {
    uint2 r = ((const uint2*)(h + (size_t)row * DIM))[l16];
    __half2 h01 = *(__half2*)&r.x;
    __half2 h23 = *(__half2*)&r.y;
    acc.x = __builtin_fmaf(__half2float(__low2half(h01)),  w, acc.x);
    acc.y = __builtin_fmaf(__half2float(__high2half(h01)), w, acc.y);
    acc.z = __builtin_fmaf(__half2float(__low2half(h23)),  w, acc.z);
    acc.w = __builtin_fmaf(__half2float(__high2half(h23)), w, acc.w);
    return acc;
}

// Full-table SpMV: 4 rows/wave (1 per 16-lane group), 16 edges in flight
// (deepened from 8: gather is L3-latency-bound, not BW-bound; padding
// slots re-read the p0 line from L1 so the waste is VALU-only).
__global__ void spmv_csr_kernel(const int* __restrict__ row_ptr,
                                const int2* __restrict__ csr_cv,
                                const ushort* __restrict__ h_src,
                                ushort* __restrict__ h_dst) {
    int wave = (int)(((long)blockIdx.x * blockDim.x + threadIdx.x) >> 6);
    int lane = threadIdx.x & 63;
    int g    = lane >> 4;
    int l16  = lane & 15;
    int r    = wave * 4 + g;
    int rc   = min(r, N_NODES - 1);
    int p0   = row_ptr[rc];
    int p1   = row_ptr[rc + 1];
    int len  = (r < N_NODES) ? (p1 - p0) : 0;
    int m = max(len, __shfl_xor(len, 16, 64));
    m = max(m, __shfl_xor(m, 32, 64));
    float4 acc = make_float4(0.f, 0.f, 0.f, 0.f);
    for (int off = 0; off < m; off += 16) {
        int2 cv[16];
        #pragma unroll
        for (int j = 0; j < 16; ++j) {
            bool k = (off + j) < len;
            cv[j] = csr_cv[k ? (p0 + off + j) : p0];
            if (!k) cv[j].y = 0;
        }
        #pragma unroll
        for (int j = 0; j < 16; ++j)
            acc = fma_mix4(h_src, cv[j].x, l16, __int_as_float(cv[j].y), acc);
    }
    if (r < N_NODES) {
        __half2 a = __floats2half2_rn(acc.x, acc.y);
        __half2 b = __floats2half2_rn(acc.z, acc.w);
        uint2 o;
        o.x = *(unsigned*)&a;
        o.y = *(unsigned*)&b;
        ((uint2*)(h_dst + (size_t)r * DIM))[l16] = o;
    }
}

// Layer-3 SpMV over BATCH ROWS ONLY (~11% of the edges): slot s in [0,2B);
// node = users[s] or N_USERS+items[s-B]. Accumulates A·h2[node] in fp32 and
// adds straight into u_acc/it_acc (slot owned by exactly one group: safe RMW).
__global__ void spmv_batch_kernel(const int* __restrict__ row_ptr,
                                  const int2* __restrict__ csr_cv,
                                  const ushort* __restrict__ h_src,
                                  const int* __restrict__ users,
                                  const int* __restrict__ items,
                                  float* __restrict__ u_acc,
                                  float* __restrict__ it_acc, int B) {
    int wave = (int)(((long)blockIdx.x * blockDim.x + threadIdx.x) >> 6);
    int lane = threadIdx.x & 63;
    int g    = lane >> 4;
    int l16  = lane & 15;
    int s    = wave * 4 + g;
    bool ok  = s < 2 * B;
    int node = 0;
    if (ok) node = (s < B) ? users[s] : (N_USERS + items[s - B]);
    int p0  = row_ptr[node];
    int p1  = row_ptr[node + 1];
    int len = ok ? (p1 - p0) : 0;
    int m = max(len, __shfl_xor(len, 16, 64));
    m = max(m, __shfl_xor(m, 32, 64));
    float4 acc = make_float4(0.f, 0.f, 0.f, 0.f);
    for (int off = 0; off < m; off += 16) {
        int2 cv[16];
        #pragma unroll
        for (int j = 0; j < 16; ++j) {
            bool k = (off + j) < len;
            cv[j] = csr_cv[k ? (p0 + off + j) : p0];
            if (!k) cv[j].y = 0;
        }
        #pragma unroll
        for (int j = 0; j < 16; ++j)
            acc = fma_mix4(h_src, cv[j].x, l16, __int_as_float(cv[j].y), acc);
    }
    if (ok) {
        float* dst = (s < B) ? (u_acc + (size_t)s * DIM)
                             : (it_acc + (size_t)(s - B) * DIM);
        float4* p = (float4*)dst + l16;
        float4 old = *p;
        old.x += acc.x; old.y += acc.y; old.z += acc.z; old.w += acc.w;
        *p = old;
    }
}

// ---------- batch-row accumulation (fp32 acc) + readout ----------

__global__ void gather_add_kernel(const ushort* __restrict__ h,
                                  const int* __restrict__ users,
                                  const int* __restrict__ items,
                                  float* __restrict__ u_acc,
                                  float* __restrict__ it_acc,
                                  int B, int first) {
    int gid  = blockIdx.x * blockDim.x + threadIdx.x;
    int b    = gid >> 4;
    int lane = gid & 15;
    if (b >= B) return;
    int u  = users[b];
    int it = N_USERS + items[b];
    uint2 ur = ((const uint2*)(h + (size_t)u  * DIM))[lane];
    uint2 ir = ((const uint2*)(h + (size_t)it * DIM))[lane];
    float2 u01 = __half22float2(*(__half2*)&ur.x);
    float2 u23 = __half22float2(*(__half2*)&ur.y);
    float2 i01 = __half22float2(*(__half2*)&ir.x);
    float2 i23 = __half22float2(*(__half2*)&ir.y);
    float4* up = (float4*)(u_acc  + (size_t)b * DIM) + lane;
    float4* ip = (float4*)(it_acc + (size_t)b * DIM) + lane;
    if (first) {
        *up = make_float4(u01.x, u01.y, u23.x, u23.y);
        *ip = make_float4(i01.x, i01.y, i23.x, i23.y);
    } else {
        float4 a = *up;
        a.x += u01.x; a.y += u01.y; a.z += u23.x; a.w += u23.y;
        *up = a;
        float4 c = *ip;
        c.x += i01.x; c.y += i01.y; c.z += i23.x; c.w += i23.y;
        *ip = c;
    }
}

__global__ void dot_kernel(const float* __restrict__ u_acc,
                           const float* __restrict__ it_acc,
                           float* __restrict__ out, int B) {
    int gid  = blockIdx.x * blockDim.x + threadIdx.x;
    int b    = gid >> 6;
    int lane = gid & 63;
    if (b >= B) return;
    float p = u_acc[(size_t)b * DIM + lane] * it_acc[(size_t)b * DIM + lane];
    #pragma unroll
    for (int off = 32; off > 0; off >>= 1)
        p += __shfl_down(p, off, 64);
    if (lane == 0) out[b] = p * (1.0f / 16.0f);
}

extern "C" void kernel_launch(void* const* d_in, const int* in_sizes, int n_in,
                              void* d_out, int out_size, void* d_ws, size_t ws_size,
                              hipStream_t stream) {
    const int*   users = (const int*)d_in[0];
    const int*   items = (const int*)d_in[1];
    const int*   erows = (const int*)d_in[2];
    const int*   ecols = (const int*)d_in[3];
    const float* evals = (const float*)d_in[4];
    const float* uemb  = (const float*)d_in[5];
    const float* iemb  = (const float*)d_in[6];
    const float* temb  = (const float*)d_in[7];
    float* out = (float*)d_out;

    const int n_edges = in_sizes[2];
    const int B       = in_sizes[0];

    const size_t h2bytes = (((size_t)N_NODES * DIM * 2 + 255) / 256) * 256;  // 38.4 MB
    const size_t abytes  = (size_t)B * DIM * sizeof(float);                  // 4.2 MB
    const size_t rpbytes = (((size_t)(N_NODES + 1) * 4 + 255) / 256) * 256;
    const size_t cvbytes = (size_t)n_edges * 8;                              // 40 MB
    const size_t mbytes  = (((size_t)M_TOT * 4 + 255) / 256) * 256;          // 1.2 MB

    char* ws = (char*)d_ws;
    size_t off = 0;
    ushort* hA      = (ushort*)(ws + off); off += h2bytes;
    ushort* hB      = (ushort*)(ws + off); off += h2bytes;
    float*  u_acc   = (float*) (ws + off); off += abytes;
    float*  it_acc  = (float*) (ws + off); off += abytes;
    int*    row_ptr = (int*)   (ws + off); off += rpbytes;
    int2*   csr_cv  = (int2*)  (ws + off); off += cvbytes;
    int2*   bkt_buf = (int2*)  (ws + off); off += cvbytes;
    int*    partial = (int*)   (ws + off); off += mbytes;
    int*    offs    = (int*)   (ws + off); off += mbytes;
    int*    psum    = (int*)   (ws + off); off += 4096;   // ~168 MB total

    dim3 blk(256);

    // ---- CSR build: zero global atomics ----
    bucket_hist_kernel<<<NB, blk, 0, stream>>>(erows, partial, n_edges);
    scanB1_kernel<<<SB, blk, 0, stream>>>(partial, psum);
    scanB2_kernel<<<1,  SB,  0, stream>>>(psum);
    scanB3_kernel<<<SB, blk, 0, stream>>>(partial, psum, offs);
    scatter1_kernel<<<NB, blk, 0, stream>>>(erows, ecols, evals, offs, bkt_buf, n_edges);
    scatter2_kernel<<<NBUCKETS, blk, 0, stream>>>(bkt_buf, offs, row_ptr, csr_cv, n_edges);

    // ---- h0 ----
    const long n4 = (long)N_NODES * DIM / 4;
    concat_f16_kernel<<<(int)((n4 + 255) / 256), blk, 0, stream>>>(uemb, iemb, temb, hA);

    const int gblocks = (B * 16 + 255) / 256;
    gather_add_kernel<<<gblocks, blk, 0, stream>>>(hA, users, items, u_acc, it_acc, B, 1);

    // ---- layers 1,2: full-table SpMV; layer 3: batch rows only ----
    const int nwaves  = (N_NODES + 3) / 4;
    const int sblocks = (int)(((long)nwaves * 64 + 255) / 256);
    ushort* src = hA;
    ushort* dst = hB;
    for (int l = 0; l < 2; ++l) {
        spmv_csr_kernel<<<sblocks, blk, 0, stream>>>(row_ptr, csr_cv, src, dst);
        gather_add_kernel<<<gblocks, blk, 0, stream>>>(dst, users, items, u_acc, it_acc, B, 0);
        ushort* t = src; src = dst; dst = t;
    }
    // src == h2
    const int bwaves  = (2 * B + 3) / 4;
    const int bblocks = (int)(((long)bwaves * 64 + 255) / 256);
    spmv_batch_kernel<<<bblocks, blk, 0, stream>>>(row_ptr, csr_cv, src,
                                                   users, items, u_acc, it_acc, B);

    dot_kernel<<<(B * 64 + 255) / 256, blk, 0, stream>>>(u_acc, it_acc, out, B);
}

// Round 3
// 591.132 us; speedup vs baseline: 1.1484x; 1.1145x over previous
//
#include <hip/hip_runtime.h>
#include <hip/hip_fp16.h>

#define N_USERS  200000
#define N_ITEMS  100000
#define N_TOPICS 100
#define N_NODES  (N_USERS + N_ITEMS + N_TOPICS)
#define DIM      64
#define BSHIFT   9                                // 512 rows per bucket
#define BROWS    (1 << BSHIFT)
#define NBUCKETS ((N_NODES + BROWS - 1) >> BSHIFT)   // 587
#define COLMASK  0x7FFFF                          // 19 bits (N_NODES < 2^19)
#define NB       512                              // binning blocks
#define NBSHIFT  9
#define M_TOT    (NBUCKETS * NB)                  // 300,544 partials
#define SB       256                              // scan blocks
#define CH       ((M_TOT + SB - 1) / SB)

// ---------- CSR build (zero global atomics) ----------

// 512 threads/block (grid fixed at NB): 2x TLP vs 256, ~1 thread/LDS counter.
__global__ void bucket_hist_kernel(const int* __restrict__ rows,
                                   int* __restrict__ partial, int n_edges) {
    __shared__ int h[NBUCKETS];
    for (int i = threadIdx.x; i < NBUCKETS; i += blockDim.x) h[i] = 0;
    __syncthreads();
    int stride = gridDim.x * blockDim.x;
    for (int e = blockIdx.x * blockDim.x + threadIdx.x; e < n_edges; e += stride)
        atomicAdd(&h[((unsigned)rows[e]) >> BSHIFT], 1);
    __syncthreads();
    for (int i = threadIdx.x; i < NBUCKETS; i += blockDim.x)
        partial[blockIdx.x * NBUCKETS + i] = h[i];
}

// Logical L = bucket*NB + block; physical = block*NBUCKETS + bucket.
__device__ __forceinline__ int phys_idx(int L) {
    return (L & (NB - 1)) * NBUCKETS + (L >> NBSHIFT);
}

__global__ void scanB1_kernel(const int* __restrict__ partial,
                              int* __restrict__ psum) {
    __shared__ int s[256];
    int tid = threadIdx.x;
    int c0 = blockIdx.x * CH;
    int c1 = min(M_TOT, c0 + CH);
    int sum = 0;
    for (int L = c0 + tid; L < c1; L += 256) sum += partial[phys_idx(L)];
    s[tid] = sum;
    __syncthreads();
    for (int off = 128; off > 0; off >>= 1) {
        if (tid < off) s[tid] += s[tid + off];
        __syncthreads();
    }
    if (tid == 0) psum[blockIdx.x] = s[0];
}

// scanB2 folded in: each block reduces psum[0..bid) itself (256 ints, cheap).
__global__ void scanB3_kernel(const int* __restrict__ partial,
                              const int* __restrict__ psum,
                              int* __restrict__ offs) {
    __shared__ int s[SB];
    __shared__ int tile[256];
    __shared__ int carry;
    int tid = threadIdx.x;
    s[tid] = (tid < blockIdx.x) ? psum[tid] : 0;
    __syncthreads();
    for (int off = 128; off > 0; off >>= 1) {
        if (tid < off) s[tid] += s[tid + off];
        __syncthreads();
    }
    if (tid == 0) carry = s[0];
    __syncthreads();
    int c0 = blockIdx.x * CH;
    int c1 = min(M_TOT, c0 + CH);
    for (int base = c0; base < c1; base += 256) {
        int L = base + tid;
        int v = (L < c1) ? partial[phys_idx(L)] : 0;
        tile[tid] = v;
        __syncthreads();
        for (int off = 1; off < 256; off <<= 1) {
            int t = (tid >= off) ? tile[tid - off] : 0;
            __syncthreads();
            tile[tid] += t;
            __syncthreads();
        }
        if (L < c1) offs[L] = carry + tile[tid] - v;
        __syncthreads();
        if (tid == 255) carry += tile[255];
        __syncthreads();
    }
}

// Bin edges into 512-row buckets at exact positions; LDS-only atomics.
// 512 threads/block, grid fixed at NB (mapping must match bucket_hist).
__global__ void scatter1_kernel(const int* __restrict__ rows,
                                const int* __restrict__ cols,
                                const float* __restrict__ vals,
                                const int* __restrict__ offs,
                                int2* __restrict__ bkt_buf, int n_edges) {
    __shared__ int lpos[NBUCKETS];
    for (int i = threadIdx.x; i < NBUCKETS; i += blockDim.x)
        lpos[i] = offs[i * NB + blockIdx.x];
    __syncthreads();
    int stride = gridDim.x * blockDim.x;
    for (int e = blockIdx.x * blockDim.x + threadIdx.x; e < n_edges; e += stride) {
        int r = rows[e];
        int b = ((unsigned)r) >> BSHIFT;
        int pos = atomicAdd(&lpos[b], 1);
        int2 p;
        p.x = cols[e] | ((r & (BROWS - 1)) << 19);
        p.y = __float_as_int(vals[e]);
        bkt_buf[pos] = p;
    }
}

// One 512-thread block per 512-row bucket: LDS row hist, scan (256 threads,
// 2 rows each), emit row_ptr, place edges into the bucket's CSR span.
__global__ void scatter2_kernel(const int2* __restrict__ bkt_buf,
                                const int* __restrict__ offs,
                                int* __restrict__ row_ptr,
                                int2* __restrict__ csr_cv, int n_edges) {
    __shared__ int lcnt[BROWS];
    __shared__ int lptr[BROWS];
    __shared__ int lfill[BROWS];
    __shared__ int s[256];
    int b = blockIdx.x;
    int t = threadIdx.x;
    int e0 = offs[b * NB];
    int e1 = (b == NBUCKETS - 1) ? n_edges : offs[(b + 1) * NB];
    lcnt[t] = 0;
    lfill[t] = 0;
    __syncthreads();
    for (int e = e0 + t; e < e1; e += blockDim.x)
        atomicAdd(&lcnt[((unsigned)bkt_buf[e].x) >> 19], 1);
    __syncthreads();
    if (t < 256) s[t] = lcnt[2 * t] + lcnt[2 * t + 1];
    __syncthreads();
    for (int off = 1; off < 256; off <<= 1) {
        int v = 0;
        if (t < 256 && t >= off) v = s[t - off];
        __syncthreads();
        if (t < 256) s[t] += v;          // inclusive over pairs
        __syncthreads();
    }
    if (t < 256) {
        int base = e0 + (t ? s[t - 1] : 0);
        int rbase = b << BSHIFT;
        int p_even = base;
        int p_odd  = base + lcnt[2 * t];
        lptr[2 * t]     = p_even;
        lptr[2 * t + 1] = p_odd;
        if (rbase + 2 * t     < N_NODES) row_ptr[rbase + 2 * t]     = p_even;
        if (rbase + 2 * t + 1 < N_NODES) row_ptr[rbase + 2 * t + 1] = p_odd;
    }
    if (b == NBUCKETS - 1 && t == 0) row_ptr[N_NODES] = n_edges;
    __syncthreads();
    for (int e = e0 + t; e < e1; e += blockDim.x) {
        int2 p = bkt_buf[e];
        int delta = ((unsigned)p.x) >> 19;
        int pos = lptr[delta] + atomicAdd(&lfill[delta], 1);
        int2 cv;
        cv.x = p.x & COLMASK;
        cv.y = p.y;
        csr_cv[pos] = cv;
    }
}

// ---------- h0 = fp16(concat(user, item, topic)) ----------
__global__ void concat_f16_kernel(const float* __restrict__ uemb,
                                  const float* __restrict__ iemb,
                                  const float* __restrict__ temb,
                                  ushort* __restrict__ h0) {
    int g = blockIdx.x * blockDim.x + threadIdx.x;     // group of 4 elems
    long base = (long)g * 4;
    if (base >= (long)N_NODES * DIM) return;
    const float* src;
    long off;
    if (base < (long)N_USERS * DIM)                 { src = uemb; off = base; }
    else if (base < (long)(N_USERS + N_ITEMS) * DIM){ src = iemb; off = base - (long)N_USERS * DIM; }
    else                                            { src = temb; off = base - (long)(N_USERS + N_ITEMS) * DIM; }
    float4 v = *(const float4*)(src + off);
    __half2 a = __floats2half2_rn(v.x, v.y);
    __half2 b = __floats2half2_rn(v.z, v.w);
    uint2 o;
    o.x = *(unsigned*)&a;
    o.y = *(unsigned*)&b;
    ((uint2*)h0)[g] = o;
}

// ---------- SpMV helpers ----------
// fmaf(half2float(h), w, acc) lowers to v_fma_mix_f32 (fp16 src, fp32 MAC).
__device__ __forceinline__ float4 fma_mix4(const ushort* __restrict__ h,
                                           int row, int l16, float w,
                                           float4 acc) {
    uint2 r = ((const uint2*)(h + (size_t)row * DIM))[l16];
    __half2 h01 = *(__half2*)&r.x;
    __half2 h23 = *(__half2*)&r.y;
    acc.x = __builtin_fmaf(__half2float(__low2half(h01)),  w, acc.x);
    acc.y = __builtin_fmaf(__half2float(__high2half(h01)), w, acc.y);
    acc.z = __builtin_fmaf(__half2float(__low2half(h23)),  w, acc.z);
    acc.w = __builtin_fmaf(__half2float(__high2half(h23)), w, acc.w);
    return acc;
}

// Full-table SpMV: 4 rows/wave (1 per 16-lane group), 8 edges in flight.
// (8-unroll is the proven optimum: 16 raised VGPR 32->40, dropped occ
// 75->59% and added padding waste -> +23% time. Do not deepen.)
__global__ void spmv_csr_kernel(const int* __restrict__ row_ptr,
                                const int2* __restrict__ csr_cv,
                                const ushort* __restrict__ h_src,
                                ushort* __restrict__ h_dst) {
    int wave = (int)(((long)blockIdx.x * blockDim.x + threadIdx.x) >> 6);
    int lane = threadIdx.x & 63;
    int g    = lane >> 4;
    int l16  = lane & 15;
    int r    = wave * 4 + g;
    int rc   = min(r, N_NODES - 1);
    int p0   = row_ptr[rc];
    int p1   = row_ptr[rc + 1];
    int len  = (r < N_NODES) ? (p1 - p0) : 0;
    int m = max(len, __shfl_xor(len, 16, 64));
    m = max(m, __shfl_xor(m, 32, 64));
    float4 acc = make_float4(0.f, 0.f, 0.f, 0.f);
    for (int off = 0; off < m; off += 8) {
        int2 cv[8];
        #pragma unroll
        for (int j = 0; j < 8; ++j) {
            bool k = (off + j) < len;
            cv[j] = csr_cv[k ? (p0 + off + j) : p0];
            if (!k) cv[j].y = 0;
        }
        #pragma unroll
        for (int j = 0; j < 8; ++j)
            acc = fma_mix4(h_src, cv[j].x, l16, __int_as_float(cv[j].y), acc);
    }
    if (r < N_NODES) {
        __half2 a = __floats2half2_rn(acc.x, acc.y);
        __half2 b = __floats2half2_rn(acc.z, acc.w);
        uint2 o;
        o.x = *(unsigned*)&a;
        o.y = *(unsigned*)&b;
        ((uint2*)(h_dst + (size_t)r * DIM))[l16] = o;
    }
}

// Layer-3 SpMV over BATCH ROWS ONLY (~11% of the edges): slot s in [0,2B);
// node = users[s] or N_USERS+items[s-B]. Accumulates A·h2[node] in fp32 and
// adds straight into u_acc/it_acc (slot owned by exactly one group: safe RMW).
__global__ void spmv_batch_kernel(const int* __restrict__ row_ptr,
                                  const int2* __restrict__ csr_cv,
                                  const ushort* __restrict__ h_src,
                                  const int* __restrict__ users,
                                  const int* __restrict__ items,
                                  float* __restrict__ u_acc,
                                  float* __restrict__ it_acc, int B) {
    int wave = (int)(((long)blockIdx.x * blockDim.x + threadIdx.x) >> 6);
    int lane = threadIdx.x & 63;
    int g    = lane >> 4;
    int l16  = lane & 15;
    int s    = wave * 4 + g;
    bool ok  = s < 2 * B;
    int node = 0;
    if (ok) node = (s < B) ? users[s] : (N_USERS + items[s - B]);
    int p0  = row_ptr[node];
    int p1  = row_ptr[node + 1];
    int len = ok ? (p1 - p0) : 0;
    int m = max(len, __shfl_xor(len, 16, 64));
    m = max(m, __shfl_xor(m, 32, 64));
    float4 acc = make_float4(0.f, 0.f, 0.f, 0.f);
    for (int off = 0; off < m; off += 8) {
        int2 cv[8];
        #pragma unroll
        for (int j = 0; j < 8; ++j) {
            bool k = (off + j) < len;
            cv[j] = csr_cv[k ? (p0 + off + j) : p0];
            if (!k) cv[j].y = 0;
        }
        #pragma unroll
        for (int j = 0; j < 8; ++j)
            acc = fma_mix4(h_src, cv[j].x, l16, __int_as_float(cv[j].y), acc);
    }
    if (ok) {
        float* dst = (s < B) ? (u_acc + (size_t)s * DIM)
                             : (it_acc + (size_t)(s - B) * DIM);
        float4* p = (float4*)dst + l16;
        float4 old = *p;
        old.x += acc.x; old.y += acc.y; old.z += acc.z; old.w += acc.w;
        *p = old;
    }
}

// ---------- batch-row accumulation (fp32 acc) + readout ----------

__global__ void gather_add_kernel(const ushort* __restrict__ h,
                                  const int* __restrict__ users,
                                  const int* __restrict__ items,
                                  float* __restrict__ u_acc,
                                  float* __restrict__ it_acc,
                                  int B, int first) {
    int gid  = blockIdx.x * blockDim.x + threadIdx.x;
    int b    = gid >> 4;
    int lane = gid & 15;
    if (b >= B) return;
    int u  = users[b];
    int it = N_USERS + items[b];
    uint2 ur = ((const uint2*)(h + (size_t)u  * DIM))[lane];
    uint2 ir = ((const uint2*)(h + (size_t)it * DIM))[lane];
    float2 u01 = __half22float2(*(__half2*)&ur.x);
    float2 u23 = __half22float2(*(__half2*)&ur.y);
    float2 i01 = __half22float2(*(__half2*)&ir.x);
    float2 i23 = __half22float2(*(__half2*)&ir.y);
    float4* up = (float4*)(u_acc  + (size_t)b * DIM) + lane;
    float4* ip = (float4*)(it_acc + (size_t)b * DIM) + lane;
    if (first) {
        *up = make_float4(u01.x, u01.y, u23.x, u23.y);
        *ip = make_float4(i01.x, i01.y, i23.x, i23.y);
    } else {
        float4 a = *up;
        a.x += u01.x; a.y += u01.y; a.z += u23.x; a.w += u23.y;
        *up = a;
        float4 c = *ip;
        c.x += i01.x; c.y += i01.y; c.z += i23.x; c.w += i23.y;
        *ip = c;
    }
}

__global__ void dot_kernel(const float* __restrict__ u_acc,
                           const float* __restrict__ it_acc,
                           float* __restrict__ out, int B) {
    int gid  = blockIdx.x * blockDim.x + threadIdx.x;
    int b    = gid >> 6;
    int lane = gid & 63;
    if (b >= B) return;
    float p = u_acc[(size_t)b * DIM + lane] * it_acc[(size_t)b * DIM + lane];
    #pragma unroll
    for (int off = 32; off > 0; off >>= 1)
        p += __shfl_down(p, off, 64);
    if (lane == 0) out[b] = p * (1.0f / 16.0f);
}

extern "C" void kernel_launch(void* const* d_in, const int* in_sizes, int n_in,
                              void* d_out, int out_size, void* d_ws, size_t ws_size,
                              hipStream_t stream) {
    const int*   users = (const int*)d_in[0];
    const int*   items = (const int*)d_in[1];
    const int*   erows = (const int*)d_in[2];
    const int*   ecols = (const int*)d_in[3];
    const float* evals = (const float*)d_in[4];
    const float* uemb  = (const float*)d_in[5];
    const float* iemb  = (const float*)d_in[6];
    const float* temb  = (const float*)d_in[7];
    float* out = (float*)d_out;

    const int n_edges = in_sizes[2];
    const int B       = in_sizes[0];

    const size_t h2bytes = (((size_t)N_NODES * DIM * 2 + 255) / 256) * 256;  // 38.4 MB
    const size_t abytes  = (size_t)B * DIM * sizeof(float);                  // 4.2 MB
    const size_t rpbytes = (((size_t)(N_NODES + 1) * 4 + 255) / 256) * 256;
    const size_t cvbytes = (size_t)n_edges * 8;                              // 40 MB
    const size_t mbytes  = (((size_t)M_TOT * 4 + 255) / 256) * 256;          // 1.2 MB

    char* ws = (char*)d_ws;
    size_t off = 0;
    ushort* hA      = (ushort*)(ws + off); off += h2bytes;
    ushort* hB      = (ushort*)(ws + off); off += h2bytes;
    float*  u_acc   = (float*) (ws + off); off += abytes;
    float*  it_acc  = (float*) (ws + off); off += abytes;
    int*    row_ptr = (int*)   (ws + off); off += rpbytes;
    int2*   csr_cv  = (int2*)  (ws + off); off += cvbytes;
    int2*   bkt_buf = (int2*)  (ws + off); off += cvbytes;
    int*    partial = (int*)   (ws + off); off += mbytes;
    int*    offs    = (int*)   (ws + off); off += mbytes;
    int*    psum    = (int*)   (ws + off); off += 4096;   // ~168 MB total

    dim3 blk(256);
    dim3 blk512(512);

    // ---- CSR build: zero global atomics ----
    bucket_hist_kernel<<<NB, blk512, 0, stream>>>(erows, partial, n_edges);
    scanB1_kernel<<<SB, blk, 0, stream>>>(partial, psum);
    scanB3_kernel<<<SB, blk, 0, stream>>>(partial, psum, offs);
    scatter1_kernel<<<NB, blk512, 0, stream>>>(erows, ecols, evals, offs, bkt_buf, n_edges);
    scatter2_kernel<<<NBUCKETS, blk512, 0, stream>>>(bkt_buf, offs, row_ptr, csr_cv, n_edges);

    // ---- h0 ----
    const long n4 = (long)N_NODES * DIM / 4;
    concat_f16_kernel<<<(int)((n4 + 255) / 256), blk, 0, stream>>>(uemb, iemb, temb, hA);

    const int gblocks = (B * 16 + 255) / 256;
    gather_add_kernel<<<gblocks, blk, 0, stream>>>(hA, users, items, u_acc, it_acc, B, 1);

    // ---- layers 1,2: full-table SpMV; layer 3: batch rows only ----
    const int nwaves  = (N_NODES + 3) / 4;
    const int sblocks = (int)(((long)nwaves * 64 + 255) / 256);
    ushort* src = hA;
    ushort* dst = hB;
    for (int l = 0; l < 2; ++l) {
        spmv_csr_kernel<<<sblocks, blk, 0, stream>>>(row_ptr, csr_cv, src, dst);
        gather_add_kernel<<<gblocks, blk, 0, stream>>>(dst, users, items, u_acc, it_acc, B, 0);
        ushort* t = src; src = dst; dst = t;
    }
    // src == h2
    const int bwaves  = (2 * B + 3) / 4;
    const int bblocks = (int)(((long)bwaves * 64 + 255) / 256);
    spmv_batch_kernel<<<bblocks, blk, 0, stream>>>(row_ptr, csr_cv, src,
                                                   users, items, u_acc, it_acc, B);

    dot_kernel<<<(B * 64 + 255) / 256, blk, 0, stream>>>(u_acc, it_acc, out, B);
}